// Round 7
// baseline (716.403 us; speedup 1.0000x reference)
//
#include <hip/hip_runtime.h>

// Entropic Sinkhorn EMD, B=2, N=4096, D=3, EPS=0.1, 20 iters.
// Round-13: BISECT. Round-12 (two-level counters + packed v_pk math, SoA)
// failed with absmax 2.6e-2; paper audit found no defect in either change,
// so isolate them. This kernel = round-10 VERBATIM (passed, absmax 0.0,
// 685us) + ONLY the two-level counter change:
//   32 sub-counters (16 blocks each) promote into ONE top counter per
//   (cloud,b) chain; consumers poll only the top line (single coalesced
//   same-line load per block per round, s_sleep(8)) instead of 32 lines.
// Round-10's FETCH=17.1MB ~= 10.5MB irreducible ring first-touch fills
// + ~6.5MB poll traffic; the poll RATE contends with phase-critical
// producer stores at the LLC. If this passes -> packed math was round-12's
// bug; if it fails -> the counter logic is (audit wrong), revert sync.

#define N     4096
#define NT    256
#define RPB   8      // rows per block -> grid (512, 2) = 1024 blocks = 4/CU
#define NGRP  32     // producer groups per (cloud,b); 512/32 = 16 blocks each
#define GRPSZ 16
#define CSTR  32     // counter stride in u32 (128 B, one line per counter)

constexpr float EPS_F  = 0.1f;
constexpr float SHIFT  = 60.0f;
constexpr float LOG_A  = -8.317766166719343f;   // -log(4096)
constexpr float C10L   = 14.426950408889634f;   // 10*log2(e)
constexpr float C20L   = 28.853900817779268f;   // 20*log2(e)
constexpr float SHIFTL = 86.56170245333781f;    // SHIFT*log2(e)
constexpr float NLN2T  = -0.06931471805599453f; // -ln2/10
constexpr float LN2    = 0.6931471805599453f;

extern "C" __device__ float __ocml_native_exp2_f32(float);

__device__ __forceinline__ float fast_exp2(float x) {
#if __has_builtin(__builtin_amdgcn_exp2f)
    return __builtin_amdgcn_exp2f(x);
#else
    return __ocml_native_exp2_f32(x);
#endif
}

__device__ __forceinline__ float rfl(float x) {
    return __int_as_float(__builtin_amdgcn_readfirstlane(__float_as_int(x)));
}

// Agent-scope (LLC-performed) store: visible to cross-XCD consumers' L2
// misses without any cache maintenance.
__device__ __forceinline__ void llc_storef(float* p, float v) {
    __hip_atomic_store(p, v, __ATOMIC_RELAXED, __HIP_MEMORY_SCOPE_AGENT);
}

// Pack {x,y,z, SHIFTL - 10L|p|^2} (CONSTANT for the whole solve); zero the
// counters (subs + tops), gRing version 0 (Sinkhorn g=0 init), and out.
// Other ring versions intentionally untouched (first-touch-after-write is
// what makes cached consumer reads coherent).
__global__ __launch_bounds__(256) void prep_kernel(
    const float* __restrict__ gen, const float* __restrict__ gt,
    float4* __restrict__ genPack, float4* __restrict__ gtPack,
    float* __restrict__ gRing0, unsigned* __restrict__ cnt,
    float* __restrict__ out)
{
    int t = blockIdx.x * 256 + threadIdx.x;   // 0 .. 16383
    if (t < 8192) cnt[t] = 0u;                // 4096 subs + tops + pad
    if (t < 8192) gRing0[t] = 0.0f;           // g*C10L = 0 initial state
    int cloud = t >> 13;
    int idx   = t & 8191;                     // b*N + j
    const float* src = cloud ? gt : gen;
    float x = src[idx * 3 + 0];
    float y = src[idx * 3 + 1];
    float z = src[idx * 3 + 2];
    float nb = -C10L * fmaf(z, z, fmaf(y, y, x * x));   // -10L|p|^2
    (cloud ? gtPack : genPack)[idx] = make_float4(x, y, z, SHIFTL + nb);
    if (t == 0) out[0] = 0.0f;
}

// Poll only the single top counter: wave 0 (all lanes, same dword -> one
// coalesced request) spins with sleep backoff; other waves park at barrier.
__device__ __forceinline__ void wait_top(const unsigned* __restrict__ top,
                                         unsigned target, int tid)
{
    if (tid < 64) {
        while (__hip_atomic_load(top, __ATOMIC_RELAXED,
                                 __HIP_MEMORY_SCOPE_AGENT) < target) {
            __builtin_amdgcn_s_sleep(8);
        }
    }
    __syncthreads();
    asm volatile("" ::: "memory");   // keep ring loads below the wait
}

// One half-sweep. Compute path BYTE-IDENTICAL to round-10 (verified,
// absmax 0.0): AoS float4 column pack + scalar ring-dual loads + scalar
// fmaf/exp2 chain. Only the sync (wait/arrive) differs.
__device__ __forceinline__ void sweep_phase(
    const float4* __restrict__ cp,   // column pack (constant, cached)
    const float*  __restrict__ h2c,  // column duals, ring version (cached)
    float*        __restrict__ h2o,  // own-row dual out (+rowBase, LLC store)
    const unsigned* __restrict__ topw,  // top counter to wait on
    unsigned*       __restrict__ sub,   // own group sub counter
    unsigned*       __restrict__ topo,  // own top counter
    unsigned wtarget, unsigned sprev,
    const float (&X)[RPB], const float (&Y)[RPB],
    const float (&Z)[RPB], const float (&S)[RPB],
    int tid, int rot, float (&sred)[RPB][4])
{
    wait_top(topw, wtarget, tid);

    float acc[RPB];
    #pragma unroll
    for (int r = 0; r < RPB; ++r) acc[r] = 0.0f;

    #pragma unroll 2
    for (int g4 = 0; g4 < 4; ++g4) {
        const int base = ((g4 + rot) & 3) * 4;   // spread first-touch lines
        float4 pr[4]; float hr[4];
        #pragma unroll
        for (int u = 0; u < 4; ++u) {
            int j = tid + NT * (base + u);
            pr[u] = cp[j];
            hr[u] = h2c[j];                      // cached (L2 after 1st touch)
        }
        #pragma unroll
        for (int u = 0; u < 4; ++u) {
            float w = pr[u].w + hr[u];
            #pragma unroll
            for (int r = 0; r < RPB; ++r) {
                float t = fmaf(Z[r], pr[u].z, w);
                t = fmaf(Y[r], pr[u].y, t);
                t = fmaf(X[r], pr[u].x, t);
                acc[r] += fast_exp2(t + S[r]);
            }
        }
    }

    #pragma unroll
    for (int r = 0; r < RPB; ++r) {
        float a = acc[r];
        a += __shfl_xor(a, 32);
        a += __shfl_xor(a, 16);
        a += __shfl_xor(a, 8);
        a += __shfl_xor(a, 4);
        a += __shfl_xor(a, 2);
        a += __shfl_xor(a, 1);
        acc[r] = a;
    }
    const int wave = tid >> 6, lane = tid & 63;
    if (lane == 0) {
        #pragma unroll
        for (int r = 0; r < RPB; ++r) sred[r][wave] = acc[r];
    }
    __syncthreads();
    if (tid < RPB) {
        float s = (sred[tid][0] + sred[tid][1]) + (sred[tid][2] + sred[tid][3]);
        float dual = EPS_F * (LOG_A + SHIFT - log2f(s) * LN2);
        llc_storef(h2o + tid, dual * C10L);
        // order: dual stores performed at LLC before the arrival inc
        asm volatile("s_waitcnt vmcnt(0)" ::: "memory");
    }
    __syncthreads();
    if (tid == 0) {
        unsigned prev = __hip_atomic_fetch_add(sub, 1u, __ATOMIC_RELAXED,
                                               __HIP_MEMORY_SCOPE_AGENT);
        if (prev == sprev)   // last block of this group this phase
            __hip_atomic_fetch_add(topo, 1u, __ATOMIC_RELAXED,
                                   __HIP_MEMORY_SCOPE_AGENT);
    }
}

__global__ __launch_bounds__(NT, 4) void sinkhorn_main(
    const float4* __restrict__ packGen, const float4* __restrict__ packGt,
    float* __restrict__ fRing,   // 20 versions x [2][N]
    float* __restrict__ gRing,   // 21 versions x [2][N]
    unsigned* __restrict__ cnt, float* __restrict__ out)
{
    const int b       = blockIdx.y;
    const int tid     = threadIdx.x;
    const int rowBase = blockIdx.x * RPB;
    const int grp     = blockIdx.x >> 4;     // 0..31, 16 blocks each
    const int rot     = blockIdx.x >> 5;     // chunk-order rotation
    __shared__ float sred[RPB][4];

    const size_t bN = (size_t)b * N;

    const float4* rpG = packGen + bN + rowBase;
    const float4* rpT = packGt  + bN + rowBase;

    float XG[RPB], YG[RPB], ZG[RPB], SG[RPB];
    float XT[RPB], YT[RPB], ZT[RPB], ST[RPB];
    #pragma unroll
    for (int r = 0; r < RPB; ++r) {
        float4 q = rpG[r];
        XG[r] = rfl(q.x * C20L);
        YG[r] = rfl(q.y * C20L);
        ZG[r] = rfl(q.z * C20L);
        SG[r] = rfl(q.w - SHIFTL);           // -10L|p_i|^2
    }
    #pragma unroll
    for (int r = 0; r < RPB; ++r) {
        float4 q = rpT[r];
        XT[r] = rfl(q.x * C20L);
        YT[r] = rfl(q.y * C20L);
        ZT[r] = rfl(q.z * C20L);
        ST[r] = rfl(q.w - SHIFTL);
    }

    const float4* cpG = packGen + bN;
    const float4* cpT = packGt  + bN;

    unsigned* subF = cnt + (size_t)(b * 2 + 0) * NGRP * CSTR + grp * CSTR;
    unsigned* subG = cnt + (size_t)(b * 2 + 1) * NGRP * CSTR + grp * CSTR;
    unsigned* topF = cnt + 4096 + (size_t)b * CSTR;
    unsigned* topG = cnt + 4096 + (size_t)(2 + b) * CSTR;

    for (unsigned t = 0; t < 20; ++t) {
        // f-update: rows=gen, cols=gt; reads gRing[t], writes fRing[t]
        sweep_phase(cpT,
                    gRing + (size_t)t * 2 * N + bN,
                    fRing + (size_t)t * 2 * N + bN + rowBase,
                    topG, subF, topF,
                    NGRP * t, GRPSZ * (t + 1) - 1,
                    XG, YG, ZG, SG, tid, rot, sred);
        // g-update: rows=gt, cols=gen; reads fRing[t], writes gRing[t+1]
        sweep_phase(cpG,
                    fRing + (size_t)t * 2 * N + bN,
                    gRing + (size_t)(t + 1) * 2 * N + bN + rowBase,
                    topF, subG, topG,
                    NGRP * (t + 1), GRPSZ * (t + 1) - 1,
                    XT, YT, ZT, ST, tid, rot, sred);
    }

    // ---- loss: += 0.5 * sum_ij exp((f_i + g_j - C_ij)/EPS) * C_ij
    wait_top(topG, NGRP * 20, tid);
    {
        const float* fFin = fRing + (size_t)19 * 2 * N + bN;
        const float* gFin = gRing + (size_t)20 * 2 * N + bN;

        float Ax[RPB], Ay[RPB], Az[RPB], Ri[RPB], F2[RPB];
        #pragma unroll
        for (int r = 0; r < RPB; ++r) {
            float4 q = rpG[r];
            Ax[r] = rfl(q.x * -2.0f);
            Ay[r] = rfl(q.y * -2.0f);
            Az[r] = rfl(q.z * -2.0f);
            Ri[r] = rfl((q.w - SHIFTL) * NLN2T);      // |p_i|^2
            F2[r] = rfl(fFin[rowBase + r]);           // f_i * C10L (cached)
        }

        float acc = 0.0f;
        #pragma unroll 2
        for (int g4 = 0; g4 < 4; ++g4) {
            const int base = ((g4 + rot) & 3) * 4;
            float4 pr[4]; float hr[4];
            #pragma unroll
            for (int u = 0; u < 4; ++u) {
                int j = tid + NT * (base + u);
                pr[u] = cpT[j];
                hr[u] = gFin[j];
            }
            #pragma unroll
            for (int u = 0; u < 4; ++u) {
                float G2 = hr[u];                        // g_j * C10L
                float rj = (pr[u].w - SHIFTL) * NLN2T;   // |p_j|^2
                #pragma unroll
                for (int r = 0; r < RPB; ++r) {
                    float cc = rj + Ri[r];
                    cc = fmaf(Az[r], pr[u].z, cc);
                    cc = fmaf(Ay[r], pr[u].y, cc);
                    cc = fmaf(Ax[r], pr[u].x, cc);
                    float arg = fmaf(cc, -C10L, G2 + F2[r]);
                    acc = fmaf(fast_exp2(arg), cc, acc);
                }
            }
        }

        acc += __shfl_xor(acc, 32);
        acc += __shfl_xor(acc, 16);
        acc += __shfl_xor(acc, 8);
        acc += __shfl_xor(acc, 4);
        acc += __shfl_xor(acc, 2);
        acc += __shfl_xor(acc, 1);
        const int wave = tid >> 6, lane = tid & 63;
        if (lane == 0) sred[0][wave] = acc;
        __syncthreads();
        if (tid == 0) {
            float t2 = (sred[0][0] + sred[0][1]) + (sred[0][2] + sred[0][3]);
            atomicAdd(out, t2 * 0.5f);
        }
    }
}

extern "C" void kernel_launch(void* const* d_in, const int* in_sizes, int n_in,
                              void* d_out, int out_size, void* d_ws, size_t ws_size,
                              hipStream_t stream) {
    const float* gen = (const float*)d_in[0];
    const float* gt  = (const float*)d_in[1];
    float* out = (float*)d_out;

    char* ws = (char*)d_ws;
    float4*   genPack = (float4*)ws;                       // [0,   128K)
    float4*   gtPack  = (float4*)(ws + 128 * 1024);        // [128K,256K)
    unsigned* cnt     = (unsigned*)(ws + 256 * 1024);      // [256K,288K) 8192 u32
    float*    fRing   = (float*)(ws + 288 * 1024);         // [288K,928K) 20x32KB
    float*    gRing   = (float*)(ws + 928 * 1024);         // [928K,1600K) 21x32KB

    prep_kernel<<<dim3(16384 / 256), 256, 0, stream>>>(
        gen, gt, genPack, gtPack, gRing, cnt, out);

    sinkhorn_main<<<dim3(N / RPB, 2), NT, 0, stream>>>(
        genPack, gtPack, fRing, gRing, cnt, out);
}